// Round 1
// baseline (635.340 us; speedup 1.0000x reference)
//
#include <hip/hip_runtime.h>
#include <math.h>

#define DIN 256
#define HDIM 128
#define NCRIT 10
#define KC 32

static inline size_t alignup(size_t x, size_t a) { return (x + a - 1) & ~(a - 1); }

// ---------- CSR build ----------
__global__ void k_hist(const int* __restrict__ dst, int E, int* __restrict__ cnt) {
    int i = blockIdx.x * 256 + threadIdx.x;
    if (i < E) atomicAdd(&cnt[dst[i]], 1);
}

__global__ void k_alloc(const int* __restrict__ cnt, int n, int* __restrict__ off,
                        int* __restrict__ total) {
    int i = blockIdx.x * 256 + threadIdx.x;
    int lane = threadIdx.x & 63;
    int v = (i < n) ? cnt[i] : 0;
    int s = v;
    // inclusive wave scan
    #pragma unroll
    for (int d = 1; d < 64; d <<= 1) {
        int t = __shfl_up(s, d, 64);
        if (lane >= d) s += t;
    }
    int excl = s - v;
    int wtot = __shfl(s, 63, 64);
    int base = 0;
    if (lane == 63) base = atomicAdd(total, wtot);
    base = __shfl(base, 63, 64);
    if (i < n) off[i] = base + excl;
}

__global__ void k_scatter(const int* __restrict__ src, const int* __restrict__ dst, int E,
                          const int* __restrict__ off, int* __restrict__ cur,
                          int* __restrict__ sidx) {
    int i = blockIdx.x * 256 + threadIdx.x;
    if (i < E) {
        int d = dst[i];
        int p = atomicAdd(&cur[d], 1);
        sidx[off[d] + p] = src[i];
    }
}

// ---------- y = x @ W_l^T  (fp32 tiled GEMM, 64 rows x 128 cols per block) ----------
__global__ __launch_bounds__(256) void k_gemm_y(const float* __restrict__ x,
                                                const float* __restrict__ Wl,
                                                int n, float* __restrict__ y) {
    __shared__ __align__(16) float xs[KC][68];   // xs[kk][r], 64 rows (transposed)
    __shared__ __align__(16) float ws[KC][132];  // ws[kk][c], 128 cols

    int t = threadIdx.x;
    int tr = t >> 4;      // 0..15
    int tc = t & 15;      // 0..15
    int node0 = blockIdx.x * 64;

    float acc[4][8];
    #pragma unroll
    for (int i = 0; i < 4; i++)
        #pragma unroll
        for (int j = 0; j < 8; j++) acc[i][j] = 0.f;

    int sr = t >> 2;            // 0..63  row for x staging
    int sk = (t & 3) * 8;       // 0,8,16,24
    int wc = t >> 3;            // 0..31  col group for W staging
    int wk = (t & 7) * 4;       // 0..28 step 4

    for (int k0 = 0; k0 < DIN; k0 += KC) {
        // stage x tile (transposed into xs[kk][r])
        {
            int gr = node0 + sr;
            float4 v0, v1;
            if (gr < n) {
                v0 = *(const float4*)&x[(size_t)gr * DIN + k0 + sk];
                v1 = *(const float4*)&x[(size_t)gr * DIN + k0 + sk + 4];
            } else {
                v0 = make_float4(0, 0, 0, 0); v1 = v0;
            }
            xs[sk + 0][sr] = v0.x; xs[sk + 1][sr] = v0.y;
            xs[sk + 2][sr] = v0.z; xs[sk + 3][sr] = v0.w;
            xs[sk + 4][sr] = v1.x; xs[sk + 5][sr] = v1.y;
            xs[sk + 6][sr] = v1.z; xs[sk + 7][sr] = v1.w;
        }
        // stage W chunk (transposed into ws[kk][c])
        #pragma unroll
        for (int jc = 0; jc < 4; jc++) {
            int c = wc + jc * 32;
            float4 v = *(const float4*)&Wl[(size_t)c * DIN + k0 + wk];
            ws[wk + 0][c] = v.x; ws[wk + 1][c] = v.y;
            ws[wk + 2][c] = v.z; ws[wk + 3][c] = v.w;
        }
        __syncthreads();
        #pragma unroll 8
        for (int kk = 0; kk < KC; kk++) {
            float4 a = *(const float4*)&xs[kk][tr * 4];
            float b[8];
            #pragma unroll
            for (int j = 0; j < 8; j++) b[j] = ws[kk][tc + j * 16];
            #pragma unroll
            for (int j = 0; j < 8; j++) {
                acc[0][j] += a.x * b[j];
                acc[1][j] += a.y * b[j];
                acc[2][j] += a.z * b[j];
                acc[3][j] += a.w * b[j];
            }
        }
        __syncthreads();
    }
    #pragma unroll
    for (int i = 0; i < 4; i++) {
        int gr = node0 + tr * 4 + i;
        if (gr < n) {
            #pragma unroll
            for (int j = 0; j < 8; j++)
                y[(size_t)gr * HDIM + tc + j * 16] = acc[i][j];
        }
    }
}

// ---------- mean-aggregate y over CSR lists (one wave per node) ----------
__global__ __launch_bounds__(256) void k_gather(const float* __restrict__ y,
                                                const int* __restrict__ off,
                                                const int* __restrict__ cnt,
                                                const int* __restrict__ sidx,
                                                int n, float* __restrict__ aggy) {
    int node = blockIdx.x * 4 + (threadIdx.x >> 6);
    if (node >= n) return;
    int lane = threadIdx.x & 63;
    int beg = off[node];
    int len = cnt[node];
    float ax = 0.f, ay = 0.f;
    int e = 0;
    for (; e + 4 <= len; e += 4) {
        int s0 = sidx[beg + e + 0];
        int s1 = sidx[beg + e + 1];
        int s2 = sidx[beg + e + 2];
        int s3 = sidx[beg + e + 3];
        float2 v0 = *(const float2*)&y[(size_t)s0 * HDIM + lane * 2];
        float2 v1 = *(const float2*)&y[(size_t)s1 * HDIM + lane * 2];
        float2 v2 = *(const float2*)&y[(size_t)s2 * HDIM + lane * 2];
        float2 v3 = *(const float2*)&y[(size_t)s3 * HDIM + lane * 2];
        ax += v0.x + v1.x + v2.x + v3.x;
        ay += v0.y + v1.y + v2.y + v3.y;
    }
    for (; e < len; ++e) {
        int s = sidx[beg + e];
        float2 v = *(const float2*)&y[(size_t)s * HDIM + lane * 2];
        ax += v.x; ay += v.y;
    }
    float inv = 1.f / fmaxf((float)len, 1.f);
    float2 r = make_float2(ax * inv, ay * inv);
    *(float2*)&aggy[(size_t)node * HDIM + lane * 2] = r;
}

// ---------- fused final: z = x@[Wr;Wres]^T, h, scores, logits ----------
__global__ __launch_bounds__(256) void k_final(
    const float* __restrict__ x, const float* __restrict__ Wr, const float* __restrict__ Wres,
    const float* __restrict__ bl, const float* __restrict__ bres, const float* __restrict__ aggy,
    const float* __restrict__ wscore, const float* __restrict__ bscore,
    const float* __restrict__ wcrit, const float* __restrict__ bcrit,
    const float* __restrict__ rr, const float* __restrict__ palpha,
    int n, float* __restrict__ outF, float* __restrict__ outL)
{
    // regions: xs [32*36], wsm [32*258] (aliased by hs [32*132] after main loop), wepi [11*132]
    __shared__ __align__(16) float smem[32 * 36 + 32 * 258 + 11 * 132];
    float* xs   = smem;
    float* wsm  = smem + 32 * 36;
    float* hs   = smem + 32 * 36;              // alias of wsm region (after final sync)
    float* wepi = smem + 32 * 36 + 32 * 258;

    int t = threadIdx.x;
    int tr = t >> 5;    // 0..7
    int tc = t & 31;    // 0..31
    int node0 = blockIdx.x * 32;

    // stage epilogue weights once
    for (int i2 = t; i2 < (NCRIT + 1) * HDIM; i2 += 256) {
        int q = i2 >> 7, c = i2 & 127;
        wepi[q * 132 + c] = (q == 0) ? wscore[c] : wcrit[(size_t)(q - 1) * HDIM + c];
    }

    float acc[4][8];
    #pragma unroll
    for (int i = 0; i < 4; i++)
        #pragma unroll
        for (int j = 0; j < 8; j++) acc[i][j] = 0.f;

    int sr = t >> 3;          // 0..31 (row for x staging / col-group for W staging)
    int sk = (t & 7) * 4;     // 0..28 step 4

    for (int k0 = 0; k0 < DIN; k0 += KC) {
        // stage x tile (transposed)
        {
            int gr = node0 + sr;
            float4 v = (gr < n) ? *(const float4*)&x[(size_t)gr * DIN + k0 + sk]
                                : make_float4(0, 0, 0, 0);
            xs[(sk + 0) * 36 + sr] = v.x;
            xs[(sk + 1) * 36 + sr] = v.y;
            xs[(sk + 2) * 36 + sr] = v.z;
            xs[(sk + 3) * 36 + sr] = v.w;
        }
        // stage [Wr;Wres] chunk (transposed), 256 cols
        #pragma unroll
        for (int jc = 0; jc < 8; jc++) {
            int c = sr + jc * 32;
            const float* wrow = (c < HDIM) ? &Wr[(size_t)c * DIN] : &Wres[(size_t)(c - HDIM) * DIN];
            float4 v = *(const float4*)&wrow[k0 + sk];
            wsm[(sk + 0) * 258 + c] = v.x;
            wsm[(sk + 1) * 258 + c] = v.y;
            wsm[(sk + 2) * 258 + c] = v.z;
            wsm[(sk + 3) * 258 + c] = v.w;
        }
        __syncthreads();
        #pragma unroll 8
        for (int kk = 0; kk < KC; kk++) {
            float4 a = *(const float4*)&xs[kk * 36 + tr * 4];
            float b[8];
            #pragma unroll
            for (int j = 0; j < 8; j++) b[j] = wsm[kk * 258 + tc + j * 32];
            #pragma unroll
            for (int j = 0; j < 8; j++) {
                acc[0][j] += a.x * b[j];
                acc[1][j] += a.y * b[j];
                acc[2][j] += a.z * b[j];
                acc[3][j] += a.w * b[j];
            }
        }
        __syncthreads();
    }

    // combine into h, store to hs (wsm region reuse — all reads finished)
    #pragma unroll
    for (int i = 0; i < 4; i++) {
        int r = tr * 4 + i;
        int node = node0 + r;
        #pragma unroll
        for (int j = 0; j < 4; j++) {
            int c = tc + j * 32;                    // 0..127
            float ag  = (node < n) ? aggy[(size_t)node * HDIM + c] : 0.f;
            float h = fmaxf(ag + bl[c] + acc[i][j], 0.f) + acc[i][j + 4] + bres[c];
            hs[r * 132 + c] = h;
        }
    }
    __syncthreads();

    float al = palpha[0];
    float a = 1.f / (1.f + expf(-al));
    float bs = bscore[0];
    for (int o = t; o < 32 * (NCRIT + 1); o += 256) {
        int r = o / (NCRIT + 1);
        int q = o - r * (NCRIT + 1);
        int node = node0 + r;
        if (node >= n) continue;
        float dot = 0.f;
        #pragma unroll 16
        for (int c = 0; c < HDIM; c++) dot += hs[r * 132 + c] * wepi[q * 132 + c];
        if (q == 0) {
            float gnn = dot + bs;
            outF[node] = a * rr[node] + (1.f - a) * gnn;
        } else {
            outL[(size_t)node * NCRIT + (q - 1)] = dot + bcrit[q - 1];
        }
    }
}

extern "C" void kernel_launch(void* const* d_in, const int* in_sizes, int n_in,
                              void* d_out, int out_size, void* d_ws, size_t ws_size,
                              hipStream_t stream) {
    const float* x      = (const float*)d_in[0];
    const int*   ei     = (const int*)d_in[1];
    const float* rr     = (const float*)d_in[2];
    const float* Wl     = (const float*)d_in[3];
    const float* bl     = (const float*)d_in[4];
    const float* Wr     = (const float*)d_in[5];
    const float* Wres   = (const float*)d_in[6];
    const float* bres   = (const float*)d_in[7];
    const float* wscore = (const float*)d_in[8];
    const float* bscore = (const float*)d_in[9];
    const float* wcrit  = (const float*)d_in[10];
    const float* bcrit  = (const float*)d_in[11];
    const float* alpha  = (const float*)d_in[12];

    int N = in_sizes[0] / DIN;
    int E = in_sizes[1] / 2;
    const int* srcv = ei;
    const int* dstv = ei + E;

    char* p = (char*)d_ws;
    int* cnt   = (int*)p; p += alignup((size_t)N * 4, 256);
    int* cur   = (int*)p; p += alignup((size_t)N * 4, 256);
    int* total = (int*)p; p += 256;
    int* off   = (int*)p; p += alignup((size_t)N * 4, 256);
    int* sidx  = (int*)p; p += alignup((size_t)E * 4, 256);
    float* y    = (float*)p; p += alignup((size_t)N * HDIM * 4, 256);
    float* aggy = (float*)p; p += alignup((size_t)N * HDIM * 4, 256);

    hipMemsetAsync(cnt, 0, (size_t)N * 4, stream);
    hipMemsetAsync(cur, 0, (size_t)N * 4, stream);
    hipMemsetAsync(total, 0, 256, stream);

    k_hist<<<(E + 255) / 256, 256, 0, stream>>>(dstv, E, cnt);
    k_alloc<<<(N + 255) / 256, 256, 0, stream>>>(cnt, N, off, total);
    k_scatter<<<(E + 255) / 256, 256, 0, stream>>>(srcv, dstv, E, off, cur, sidx);
    k_gemm_y<<<(N + 63) / 64, 256, 0, stream>>>(x, Wl, N, y);
    k_gather<<<(N + 3) / 4, 256, 0, stream>>>(y, off, cnt, sidx, N, aggy);

    float* outF = (float*)d_out;
    float* outL = outF + N;
    k_final<<<(N + 31) / 32, 256, 0, stream>>>(x, Wr, Wres, bl, bres, aggy,
                                               wscore, bscore, wcrit, bcrit,
                                               rr, alpha, N, outF, outL);
}

// Round 2
// 402.282 us; speedup vs baseline: 1.5793x; 1.5793x over previous
//
#include <hip/hip_runtime.h>
#include <math.h>

#define DIN 256
#define HDIM 128
#define NCRIT 10

typedef __bf16 bf16;
typedef bf16 bf16x8 __attribute__((ext_vector_type(8)));
typedef float f32x4 __attribute__((ext_vector_type(4)));

static inline size_t alignup(size_t x, size_t a) { return (x + a - 1) & ~(a - 1); }

__device__ inline float bflo(unsigned v) { return __uint_as_float(v << 16); }
__device__ inline float bfhi(unsigned v) { return __uint_as_float(v & 0xffff0000u); }

// ---------- CSR build ----------
__global__ void k_hist(const int* __restrict__ dst, int E, int* __restrict__ cnt) {
    int i = blockIdx.x * 256 + threadIdx.x;
    if (i < E) atomicAdd(&cnt[dst[i]], 1);
}

__global__ void k_alloc(const int* __restrict__ cnt, int n, int* __restrict__ off,
                        int* __restrict__ total) {
    int i = blockIdx.x * 256 + threadIdx.x;
    int lane = threadIdx.x & 63;
    int v = (i < n) ? cnt[i] : 0;
    int s = v;
    #pragma unroll
    for (int d = 1; d < 64; d <<= 1) {
        int t = __shfl_up(s, d, 64);
        if (lane >= d) s += t;
    }
    int excl = s - v;
    int wtot = __shfl(s, 63, 64);
    int base = 0;
    if (lane == 63) base = atomicAdd(total, wtot);
    base = __shfl(base, 63, 64);
    if (i < n) off[i] = base + excl;
}

__global__ void k_scatter(const int* __restrict__ src, const int* __restrict__ dst, int E,
                          const int* __restrict__ off, int* __restrict__ cur,
                          int* __restrict__ sidx) {
    int i = blockIdx.x * 256 + threadIdx.x;
    if (i < E) {
        int d = dst[i];
        int p = atomicAdd(&cur[d], 1);
        sidx[off[d] + p] = src[i];
    }
}

// ---------- weight concat + bf16 convert: Wcat[384][256] = [Wl; Wr; Wres] ----------
__global__ void k_wconv(const float* __restrict__ Wl, const float* __restrict__ Wr,
                        const float* __restrict__ Wres, bf16* __restrict__ Wcat) {
    int i = blockIdx.x * 256 + threadIdx.x;   // element-group of 4
    int base = i * 4;
    if (base >= 384 * 256) return;
    int r = base >> 8;
    int c = base & 255;
    const float* W = (r < 128) ? Wl : ((r < 256) ? Wr : Wres);
    float4 v = *(const float4*)&W[(size_t)(r & 127) * 256 + c];
    bf16* o = &Wcat[base];
    o[0] = (bf16)v.x; o[1] = (bf16)v.y; o[2] = (bf16)v.z; o[3] = (bf16)v.w;
}

// ---------- fused MFMA GEMM: [y | z] = x @ Wcat^T  (bf16 out) ----------
// grid: (ceil(N/128), 3); by=0 -> y (Wl), by=1,2 -> z halves (Wr, Wres)
__global__ __launch_bounds__(256) void k_gemm(const float* __restrict__ x,
                                              const bf16* __restrict__ Wcat, int n,
                                              bf16* __restrict__ y, bf16* __restrict__ z) {
    __shared__ __align__(16) bf16 smem[128 * 136];     // 34.8 KB (As+Bs alias Cs)
    bf16* As = smem;           // [128 rows][64 k], XOR-swizzled 16B groups
    bf16* Bs = smem + 8192;    // [128 cols][64 k], XOR-swizzled
    bf16* Cs = smem;           // [128][136] epilogue transpose

    int t = threadIdx.x;
    int wv = t >> 6, lane = t & 63;
    int wr = wv >> 1, wc = wv & 1;
    int node0 = blockIdx.x * 128;
    int by = blockIdx.y;
    const bf16* Wb = Wcat + (size_t)by * 128 * 256;

    f32x4 acc[4][4] = {};

    int a_kg = t & 7;          // k-group 0..7 (8 bf16 each)
    int a_r0 = t >> 3;         // 0..31
    int b_c0 = t >> 2;         // 0..63
    int b_kg2 = (t & 3) * 2;

    for (int k0 = 0; k0 < DIN; k0 += 64) {
        // stage A: x fp32 -> bf16, swizzled
        #pragma unroll
        for (int p = 0; p < 4; p++) {
            int r = a_r0 + p * 32;
            int gr = node0 + r;
            float4 v0, v1;
            if (gr < n) {
                const float* xp = &x[(size_t)gr * DIN + k0 + a_kg * 8];
                v0 = *(const float4*)xp;
                v1 = *(const float4*)(xp + 4);
            } else {
                v0 = make_float4(0, 0, 0, 0); v1 = v0;
            }
            bf16x8 w;
            w[0] = (bf16)v0.x; w[1] = (bf16)v0.y; w[2] = (bf16)v0.z; w[3] = (bf16)v0.w;
            w[4] = (bf16)v1.x; w[5] = (bf16)v1.y; w[6] = (bf16)v1.z; w[7] = (bf16)v1.w;
            *(bf16x8*)&As[r * 64 + ((a_kg ^ (r & 7)) << 3)] = w;
        }
        // stage B: weights already bf16
        #pragma unroll
        for (int p = 0; p < 2; p++) {
            int c = b_c0 + p * 64;
            #pragma unroll
            for (int q = 0; q < 2; q++) {
                int kg = b_kg2 + q;
                bf16x8 w = *(const bf16x8*)&Wb[(size_t)c * DIN + k0 + kg * 8];
                *(bf16x8*)&Bs[c * 64 + ((kg ^ (c & 7)) << 3)] = w;
            }
        }
        __syncthreads();
        #pragma unroll
        for (int kf = 0; kf < 2; kf++) {
            bf16x8 a[4], b[4];
            int kg = kf * 4 + (lane >> 4);
            #pragma unroll
            for (int m = 0; m < 4; m++) {
                int r = wr * 64 + m * 16 + (lane & 15);
                a[m] = *(const bf16x8*)&As[r * 64 + ((kg ^ (r & 7)) << 3)];
            }
            #pragma unroll
            for (int nn = 0; nn < 4; nn++) {
                int c = wc * 64 + nn * 16 + (lane & 15);
                b[nn] = *(const bf16x8*)&Bs[c * 64 + ((kg ^ (c & 7)) << 3)];
            }
            #pragma unroll
            for (int m = 0; m < 4; m++)
                #pragma unroll
                for (int nn = 0; nn < 4; nn++)
                    acc[m][nn] = __builtin_amdgcn_mfma_f32_16x16x32_bf16(
                        a[m], b[nn], acc[m][nn], 0, 0, 0);
        }
        __syncthreads();
    }

    // acc -> Cs (bf16), MFMA C/D layout: col=lane&15, row=(lane>>4)*4+j
    #pragma unroll
    for (int m = 0; m < 4; m++) {
        #pragma unroll
        for (int nn = 0; nn < 4; nn++) {
            int col = wc * 64 + nn * 16 + (lane & 15);
            int r0 = wr * 64 + m * 16 + ((lane >> 4) << 2);
            #pragma unroll
            for (int j = 0; j < 4; j++)
                Cs[(r0 + j) * 136 + col] = (bf16)acc[m][nn][j];
        }
    }
    __syncthreads();

    // coalesced global store: 16 threads/row x 16B
    int r0 = t >> 4, cc = (t & 15) * 8;
    #pragma unroll
    for (int p = 0; p < 8; p++) {
        int r = r0 + p * 16;
        int gr = node0 + r;
        if (gr >= n) continue;
        uint4 v = *(const uint4*)&Cs[r * 136 + cc];
        if (by == 0)
            *(uint4*)&y[(size_t)gr * HDIM + cc] = v;
        else
            *(uint4*)&z[(size_t)gr * 2 * HDIM + (by - 1) * HDIM + cc] = v;
    }
}

// ---------- fused gather + epilogue: one wave per node ----------
__global__ __launch_bounds__(256) void k_gather(
    const bf16* __restrict__ y, const bf16* __restrict__ z,
    const int* __restrict__ off, const int* __restrict__ cnt, const int* __restrict__ sidx,
    const float* __restrict__ bl, const float* __restrict__ bres,
    const float* __restrict__ wscore, const float* __restrict__ bscore,
    const float* __restrict__ wcrit, const float* __restrict__ bcrit,
    const float* __restrict__ rrs, const float* __restrict__ palpha,
    int n, float* __restrict__ outF, float* __restrict__ outL)
{
    __shared__ float ws[(NCRIT + 1) * HDIM];
    int t = threadIdx.x;
    for (int i = t; i < (NCRIT + 1) * HDIM; i += 256) {
        int q = i >> 7, c = i & 127;
        ws[i] = (q == 0) ? wscore[c] : wcrit[(size_t)(q - 1) * HDIM + c];
    }
    __syncthreads();

    int node = blockIdx.x * 4 + (t >> 6);
    if (node >= n) return;
    int lane = t & 63;

    int beg = off[node];
    int len = cnt[node];
    float a0 = 0.f, a1 = 0.f;
    int e = 0;
    for (; e + 4 <= len; e += 4) {
        int s0 = sidx[beg + e + 0];
        int s1 = sidx[beg + e + 1];
        int s2 = sidx[beg + e + 2];
        int s3 = sidx[beg + e + 3];
        unsigned v0 = *(const unsigned*)&y[(size_t)s0 * HDIM + lane * 2];
        unsigned v1 = *(const unsigned*)&y[(size_t)s1 * HDIM + lane * 2];
        unsigned v2 = *(const unsigned*)&y[(size_t)s2 * HDIM + lane * 2];
        unsigned v3 = *(const unsigned*)&y[(size_t)s3 * HDIM + lane * 2];
        a0 += bflo(v0) + bflo(v1) + bflo(v2) + bflo(v3);
        a1 += bfhi(v0) + bfhi(v1) + bfhi(v2) + bfhi(v3);
    }
    for (; e < len; ++e) {
        int s = sidx[beg + e];
        unsigned v = *(const unsigned*)&y[(size_t)s * HDIM + lane * 2];
        a0 += bflo(v);
        a1 += bfhi(v);
    }
    float inv = 1.f / fmaxf((float)len, 1.f);
    float ag0 = a0 * inv, ag1 = a1 * inv;

    unsigned zr = *(const unsigned*)&z[(size_t)node * 2 * HDIM + lane * 2];
    unsigned zs = *(const unsigned*)&z[(size_t)node * 2 * HDIM + HDIM + lane * 2];
    float2 blv = *(const float2*)&bl[lane * 2];
    float2 brv = *(const float2*)&bres[lane * 2];
    float h0 = fmaxf(ag0 + blv.x + bflo(zr), 0.f) + bflo(zs) + brv.x;
    float h1 = fmaxf(ag1 + blv.y + bfhi(zr), 0.f) + bfhi(zs) + brv.y;

    float p[NCRIT + 1];
    #pragma unroll
    for (int q = 0; q < NCRIT + 1; q++) {
        float2 w = *(const float2*)&ws[q * HDIM + lane * 2];
        p[q] = h0 * w.x + h1 * w.y;
    }
    #pragma unroll
    for (int q = 0; q < NCRIT + 1; q++) {
        #pragma unroll
        for (int d = 32; d >= 1; d >>= 1)
            p[q] += __shfl_xor(p[q], d, 64);
    }
    if (lane == 0) {
        float al = palpha[0];
        float a = 1.f / (1.f + expf(-al));
        outF[node] = a * rrs[node] + (1.f - a) * (p[0] + bscore[0]);
        #pragma unroll
        for (int q = 1; q < NCRIT + 1; q++)
            outL[(size_t)node * NCRIT + q - 1] = p[q] + bcrit[q - 1];
    }
}

extern "C" void kernel_launch(void* const* d_in, const int* in_sizes, int n_in,
                              void* d_out, int out_size, void* d_ws, size_t ws_size,
                              hipStream_t stream) {
    const float* x      = (const float*)d_in[0];
    const int*   ei     = (const int*)d_in[1];
    const float* rrs    = (const float*)d_in[2];
    const float* Wl     = (const float*)d_in[3];
    const float* bl     = (const float*)d_in[4];
    const float* Wr     = (const float*)d_in[5];
    const float* Wres   = (const float*)d_in[6];
    const float* bres   = (const float*)d_in[7];
    const float* wscore = (const float*)d_in[8];
    const float* bscore = (const float*)d_in[9];
    const float* wcrit  = (const float*)d_in[10];
    const float* bcrit  = (const float*)d_in[11];
    const float* alpha  = (const float*)d_in[12];

    int N = in_sizes[0] / DIN;
    int E = in_sizes[1] / 2;
    const int* srcv = ei;
    const int* dstv = ei + E;

    char* p = (char*)d_ws;
    int* cnt   = (int*)p; p += alignup((size_t)N * 4, 256);
    int* cur   = (int*)p; p += alignup((size_t)N * 4, 256);
    int* total = (int*)p; p += 256;
    int* off   = (int*)p; p += alignup((size_t)N * 4, 256);
    int* sidx  = (int*)p; p += alignup((size_t)E * 4, 256);
    bf16* Wcat = (bf16*)p; p += alignup((size_t)384 * DIN * 2, 256);
    bf16* y    = (bf16*)p; p += alignup((size_t)N * HDIM * 2, 256);
    bf16* z    = (bf16*)p; p += alignup((size_t)N * 2 * HDIM * 2, 256);

    hipMemsetAsync(cnt, 0, (size_t)N * 4, stream);
    hipMemsetAsync(cur, 0, (size_t)N * 4, stream);
    hipMemsetAsync(total, 0, 256, stream);

    k_hist<<<(E + 255) / 256, 256, 0, stream>>>(dstv, E, cnt);
    k_alloc<<<(N + 255) / 256, 256, 0, stream>>>(cnt, N, off, total);
    k_scatter<<<(E + 255) / 256, 256, 0, stream>>>(srcv, dstv, E, off, cur, sidx);
    k_wconv<<<(384 * 256 / 4 + 255) / 256, 256, 0, stream>>>(Wl, Wr, Wres, Wcat);

    dim3 ggrid((N + 127) / 128, 3);
    k_gemm<<<ggrid, 256, 0, stream>>>(x, Wcat, N, y, z);

    float* outF = (float*)d_out;
    float* outL = outF + N;
    k_gather<<<(N + 3) / 4, 256, 0, stream>>>(y, z, off, cnt, sidx, bl, bres,
                                              wscore, bscore, wcrit, bcrit,
                                              rrs, alpha, N, outF, outL);
}

// Round 3
// 391.869 us; speedup vs baseline: 1.6213x; 1.0266x over previous
//
#include <hip/hip_runtime.h>
#include <math.h>

#define DIN 256
#define HDIM 128
#define NCRIT 10

typedef __bf16 bf16;
typedef bf16 bf16x8 __attribute__((ext_vector_type(8)));
typedef float f32x4 __attribute__((ext_vector_type(4)));

static inline size_t alignup(size_t x, size_t a) { return (x + a - 1) & ~(a - 1); }

__device__ inline float bflo(unsigned v) { return __uint_as_float(v << 16); }
__device__ inline float bfhi(unsigned v) { return __uint_as_float(v & 0xffff0000u); }

__device__ inline bf16x8 cvt8(float4 v0, float4 v1) {
    bf16x8 w;
    w[0] = (bf16)v0.x; w[1] = (bf16)v0.y; w[2] = (bf16)v0.z; w[3] = (bf16)v0.w;
    w[4] = (bf16)v1.x; w[5] = (bf16)v1.y; w[6] = (bf16)v1.z; w[7] = (bf16)v1.w;
    return w;
}

__device__ inline void acc8(float* a, uint4 v) {
    a[0] += bflo(v.x); a[1] += bfhi(v.x);
    a[2] += bflo(v.y); a[3] += bfhi(v.y);
    a[4] += bflo(v.z); a[5] += bfhi(v.z);
    a[6] += bflo(v.w); a[7] += bfhi(v.w);
}

// ---------- CSR build ----------
__global__ void k_hist(const int* __restrict__ dst, int E, int* __restrict__ cnt) {
    int i = blockIdx.x * 256 + threadIdx.x;
    if (i < E) atomicAdd(&cnt[dst[i]], 1);
}

__global__ void k_alloc(const int* __restrict__ cnt, int n, int* __restrict__ off,
                        int* __restrict__ total) {
    int i = blockIdx.x * 256 + threadIdx.x;
    int lane = threadIdx.x & 63;
    int v = (i < n) ? cnt[i] : 0;
    int s = v;
    #pragma unroll
    for (int d = 1; d < 64; d <<= 1) {
        int t = __shfl_up(s, d, 64);
        if (lane >= d) s += t;
    }
    int excl = s - v;
    int wtot = __shfl(s, 63, 64);
    int base = 0;
    if (lane == 63) base = atomicAdd(total, wtot);
    base = __shfl(base, 63, 64);
    if (i < n) off[i] = base + excl;
}

__global__ void k_scatter(const int* __restrict__ src, const int* __restrict__ dst, int E,
                          const int* __restrict__ off, int* __restrict__ cur,
                          int* __restrict__ sidx) {
    int i = blockIdx.x * 256 + threadIdx.x;
    if (i < E) {
        int d = dst[i];
        int p = atomicAdd(&cur[d], 1);
        sidx[off[d] + p] = src[i];
    }
}

// ---------- weight concat + bf16 convert: Wcat[384][256] = [Wl; Wr; Wres] ----------
__global__ void k_wconv(const float* __restrict__ Wl, const float* __restrict__ Wr,
                        const float* __restrict__ Wres, bf16* __restrict__ Wcat) {
    int i = blockIdx.x * 256 + threadIdx.x;   // element-group of 4
    int base = i * 4;
    if (base >= 384 * 256) return;
    int r = base >> 8;
    int c = base & 255;
    const float* W = (r < 128) ? Wl : ((r < 256) ? Wr : Wres);
    float4 v = *(const float4*)&W[(size_t)(r & 127) * 256 + c];
    bf16* o = &Wcat[base];
    o[0] = (bf16)v.x; o[1] = (bf16)v.y; o[2] = (bf16)v.z; o[3] = (bf16)v.w;
}

// ---------- single-pass MFMA GEMM: [y | z] = x @ Wcat^T (BM=64, BN=384, BK=64) ----------
__global__ __launch_bounds__(256) void k_gemm(const float* __restrict__ x,
                                              const bf16* __restrict__ Wcat, int n,
                                              bf16* __restrict__ y, bf16* __restrict__ z) {
    __shared__ __align__(16) bf16 smem[64 * 64 + 384 * 64];  // 56 KB
    bf16* As = smem;            // [64 rows][64 k] XOR-swizzled 16B groups
    bf16* Bs = smem + 64 * 64;  // [384 cols][64 k] XOR-swizzled
    bf16* Cs = smem;            // [64][392] epilogue (aliases As/Bs)

    int t = threadIdx.x;
    int wv = t >> 6, lane = t & 63;
    int node0 = blockIdx.x * 64;

    f32x4 acc[4][6] = {};

    int a_r = t >> 2;          // 0..63
    int a_kq = t & 3;          // 16-float chunk
    int b_kg = t & 7;          // k-group (8 bf16)
    int b_c0 = t >> 3;         // 0..31

    for (int k0 = 0; k0 < DIN; k0 += 64) {
        // stage A: x fp32 -> bf16, swizzled
        {
            int gr = node0 + a_r;
            float4 v0, v1, v2, v3;
            if (gr < n) {
                const float* xp = &x[(size_t)gr * DIN + k0 + a_kq * 16];
                v0 = *(const float4*)xp;       v1 = *(const float4*)(xp + 4);
                v2 = *(const float4*)(xp + 8); v3 = *(const float4*)(xp + 12);
            } else {
                v0 = make_float4(0, 0, 0, 0); v1 = v0; v2 = v0; v3 = v0;
            }
            int kg0 = a_kq * 2;
            *(bf16x8*)&As[a_r * 64 + ((kg0 ^ (a_r & 7)) << 3)] = cvt8(v0, v1);
            *(bf16x8*)&As[a_r * 64 + (((kg0 + 1) ^ (a_r & 7)) << 3)] = cvt8(v2, v3);
        }
        // stage B: 384 rows x 8 kgs / 256 threads = 12 chunks each
        #pragma unroll
        for (int p = 0; p < 12; p++) {
            int c = b_c0 + p * 32;
            bf16x8 w = *(const bf16x8*)&Wcat[(size_t)c * DIN + k0 + b_kg * 8];
            *(bf16x8*)&Bs[c * 64 + ((b_kg ^ (c & 7)) << 3)] = w;
        }
        __syncthreads();
        #pragma unroll
        for (int kf = 0; kf < 2; kf++) {
            int kg = kf * 4 + (lane >> 4);
            bf16x8 a[4], b[6];
            #pragma unroll
            for (int m = 0; m < 4; m++) {
                int r = m * 16 + (lane & 15);
                a[m] = *(const bf16x8*)&As[r * 64 + ((kg ^ (r & 7)) << 3)];
            }
            #pragma unroll
            for (int nn = 0; nn < 6; nn++) {
                int c = wv * 96 + nn * 16 + (lane & 15);
                b[nn] = *(const bf16x8*)&Bs[c * 64 + ((kg ^ (c & 7)) << 3)];
            }
            #pragma unroll
            for (int m = 0; m < 4; m++)
                #pragma unroll
                for (int nn = 0; nn < 6; nn++)
                    acc[m][nn] = __builtin_amdgcn_mfma_f32_16x16x32_bf16(
                        a[m], b[nn], acc[m][nn], 0, 0, 0);
        }
        __syncthreads();
    }

    // acc -> Cs (bf16); C/D layout: col=lane&15, row=(lane>>4)*4+j
    #pragma unroll
    for (int m = 0; m < 4; m++) {
        #pragma unroll
        for (int nn = 0; nn < 6; nn++) {
            int col = wv * 96 + nn * 16 + (lane & 15);
            int r0 = m * 16 + ((lane >> 4) << 2);
            #pragma unroll
            for (int j = 0; j < 4; j++)
                Cs[(r0 + j) * 392 + col] = (bf16)acc[m][nn][j];
        }
    }
    __syncthreads();

    // coalesced stores: per row, 4 threads cover contiguous 64B per iteration
    {
        int r = t >> 2;
        int gr = node0 + r;
        if (gr < n) {
            #pragma unroll
            for (int u = 0; u < 4; u++) {
                int c = (t & 3) * 8 + u * 32;
                uint4 v = *(const uint4*)&Cs[r * 392 + c];
                *(uint4*)&y[(size_t)gr * HDIM + c] = v;
            }
            #pragma unroll
            for (int u = 0; u < 8; u++) {
                int c = (t & 3) * 8 + u * 32;
                uint4 v = *(const uint4*)&Cs[r * 392 + 128 + c];
                *(uint4*)&z[(size_t)gr * 2 * HDIM + c] = v;
            }
        }
    }
}

// ---------- fused gather + epilogue: one wave per node, 16B/lane gather ----------
__global__ __launch_bounds__(256) void k_gather(
    const bf16* __restrict__ y, const bf16* __restrict__ z,
    const int* __restrict__ off, const int* __restrict__ cnt, const int* __restrict__ sidx,
    const float* __restrict__ bl, const float* __restrict__ bres,
    const float* __restrict__ wscore, const float* __restrict__ bscore,
    const float* __restrict__ wcrit, const float* __restrict__ bcrit,
    const float* __restrict__ rrs, const float* __restrict__ palpha,
    int n, float* __restrict__ outF, float* __restrict__ outL)
{
    __shared__ float ws[(NCRIT + 1) * HDIM];
    int t = threadIdx.x;
    for (int i = t; i < (NCRIT + 1) * HDIM; i += 256) {
        int q = i >> 7, c = i & 127;
        ws[i] = (q == 0) ? wscore[c] : wcrit[(size_t)(q - 1) * HDIM + c];
    }
    __syncthreads();

    int node = blockIdx.x * 4 + (t >> 6);
    if (node >= n) return;
    int lane = t & 63;
    int q4 = lane >> 4;    // which edge in group of 4
    int c16 = lane & 15;   // column group: cols c16*8 .. c16*8+7

    const char* ybase = (const char*)y + c16 * 16;
    int beg = off[node], len = cnt[node];
    float a[8] = {};
    int e = 0;
    for (; e + 8 <= len; e += 8) {
        int s0 = sidx[beg + e + q4];
        int s1 = sidx[beg + e + 4 + q4];
        uint4 v0 = *(const uint4*)(ybase + ((unsigned)s0 << 8));
        uint4 v1 = *(const uint4*)(ybase + ((unsigned)s1 << 8));
        acc8(a, v0); acc8(a, v1);
    }
    if (e + 4 <= len) {
        int s0 = sidx[beg + e + q4];
        uint4 v0 = *(const uint4*)(ybase + ((unsigned)s0 << 8));
        acc8(a, v0);
        e += 4;
    }
    int rem = len - e;   // 0..3
    if (rem > 0) {
        int s0 = sidx[beg + e + (q4 < rem ? q4 : rem - 1)];
        uint4 v0 = *(const uint4*)(ybase + ((unsigned)s0 << 8));
        if (q4 < rem) acc8(a, v0);
    }
    // combine the 4 quarter-sums
    #pragma unroll
    for (int j = 0; j < 8; j++) {
        a[j] += __shfl_xor(a[j], 16, 64);
        a[j] += __shfl_xor(a[j], 32, 64);
    }
    float inv = 1.f / fmaxf((float)len, 1.f);

    uint4 zr = *(const uint4*)&z[(size_t)node * 2 * HDIM + c16 * 8];
    uint4 zs = *(const uint4*)&z[(size_t)node * 2 * HDIM + HDIM + c16 * 8];
    float4 b0 = *(const float4*)&bl[c16 * 8];
    float4 b1 = *(const float4*)&bl[c16 * 8 + 4];
    float4 r0 = *(const float4*)&bres[c16 * 8];
    float4 r1 = *(const float4*)&bres[c16 * 8 + 4];
    float zl[8] = {bflo(zr.x), bfhi(zr.x), bflo(zr.y), bfhi(zr.y),
                   bflo(zr.z), bfhi(zr.z), bflo(zr.w), bfhi(zr.w)};
    float zv[8] = {bflo(zs.x), bfhi(zs.x), bflo(zs.y), bfhi(zs.y),
                   bflo(zs.z), bfhi(zs.z), bflo(zs.w), bfhi(zs.w)};
    float blv[8] = {b0.x, b0.y, b0.z, b0.w, b1.x, b1.y, b1.z, b1.w};
    float brv[8] = {r0.x, r0.y, r0.z, r0.w, r1.x, r1.y, r1.z, r1.w};

    float h[8];
    #pragma unroll
    for (int j = 0; j < 8; j++)
        h[j] = fmaxf(a[j] * inv + blv[j] + zl[j], 0.f) + zv[j] + brv[j];

    float p[NCRIT + 1];
    #pragma unroll
    for (int q = 0; q < NCRIT + 1; q++) {
        const float* wp = &ws[q * HDIM + c16 * 8];
        float s = 0.f;
        #pragma unroll
        for (int j = 0; j < 8; j++) s += h[j] * wp[j];
        p[q] = s;
    }
    #pragma unroll
    for (int q = 0; q < NCRIT + 1; q++) {
        #pragma unroll
        for (int d = 8; d >= 1; d >>= 1)
            p[q] += __shfl_xor(p[q], d, 64);
    }
    if (lane == 0) {
        float al = palpha[0];
        float aa = 1.f / (1.f + expf(-al));
        outF[node] = aa * rrs[node] + (1.f - aa) * (p[0] + bscore[0]);
        #pragma unroll
        for (int q = 1; q < NCRIT + 1; q++)
            outL[(size_t)node * NCRIT + q - 1] = p[q] + bcrit[q - 1];
    }
}

extern "C" void kernel_launch(void* const* d_in, const int* in_sizes, int n_in,
                              void* d_out, int out_size, void* d_ws, size_t ws_size,
                              hipStream_t stream) {
    const float* x      = (const float*)d_in[0];
    const int*   ei     = (const int*)d_in[1];
    const float* rrs    = (const float*)d_in[2];
    const float* Wl     = (const float*)d_in[3];
    const float* bl     = (const float*)d_in[4];
    const float* Wr     = (const float*)d_in[5];
    const float* Wres   = (const float*)d_in[6];
    const float* bres   = (const float*)d_in[7];
    const float* wscore = (const float*)d_in[8];
    const float* bscore = (const float*)d_in[9];
    const float* wcrit  = (const float*)d_in[10];
    const float* bcrit  = (const float*)d_in[11];
    const float* alpha  = (const float*)d_in[12];

    int N = in_sizes[0] / DIN;
    int E = in_sizes[1] / 2;
    const int* srcv = ei;
    const int* dstv = ei + E;

    char* p = (char*)d_ws;
    int* cnt   = (int*)p; p += alignup((size_t)N * 4, 256);
    int* cur   = (int*)p; p += alignup((size_t)N * 4, 256);
    int* total = (int*)p; p += 256;
    int* off   = (int*)p; p += alignup((size_t)N * 4, 256);
    int* sidx  = (int*)p; p += alignup((size_t)E * 4, 256);
    bf16* Wcat = (bf16*)p; p += alignup((size_t)384 * DIN * 2, 256);
    bf16* y    = (bf16*)p; p += alignup((size_t)N * HDIM * 2, 256);
    bf16* z    = (bf16*)p; p += alignup((size_t)N * 2 * HDIM * 2, 256);

    hipMemsetAsync(cnt, 0, (size_t)N * 4, stream);
    hipMemsetAsync(cur, 0, (size_t)N * 4, stream);
    hipMemsetAsync(total, 0, 256, stream);

    k_hist<<<(E + 255) / 256, 256, 0, stream>>>(dstv, E, cnt);
    k_alloc<<<(N + 255) / 256, 256, 0, stream>>>(cnt, N, off, total);
    k_scatter<<<(E + 255) / 256, 256, 0, stream>>>(srcv, dstv, E, off, cur, sidx);
    k_wconv<<<(384 * 256 / 4 + 255) / 256, 256, 0, stream>>>(Wl, Wr, Wres, Wcat);

    k_gemm<<<(N + 63) / 64, 256, 0, stream>>>(x, Wcat, N, y, z);

    float* outF = (float*)d_out;
    float* outL = outF + N;
    k_gather<<<(N + 3) / 4, 256, 0, stream>>>(y, z, off, cnt, sidx, bl, bres,
                                              wscore, bscore, wcrit, bcrit,
                                              rrs, alpha, N, outF, outL);
}

// Round 4
// 388.742 us; speedup vs baseline: 1.6343x; 1.0080x over previous
//
#include <hip/hip_runtime.h>
#include <math.h>

#define DIN 256
#define HDIM 128
#define NCRIT 10

typedef __bf16 bf16;
typedef bf16 bf16x8 __attribute__((ext_vector_type(8)));
typedef float f32x4 __attribute__((ext_vector_type(4)));

static inline size_t alignup(size_t x, size_t a) { return (x + a - 1) & ~(a - 1); }

__device__ inline float bflo(unsigned v) { return __uint_as_float(v << 16); }
__device__ inline float bfhi(unsigned v) { return __uint_as_float(v & 0xffff0000u); }

__device__ inline bf16x8 cvt8(float4 v0, float4 v1) {
    bf16x8 w;
    w[0] = (bf16)v0.x; w[1] = (bf16)v0.y; w[2] = (bf16)v0.z; w[3] = (bf16)v0.w;
    w[4] = (bf16)v1.x; w[5] = (bf16)v1.y; w[6] = (bf16)v1.z; w[7] = (bf16)v1.w;
    return w;
}

__device__ inline void acc8(float* a, uint4 v) {
    a[0] += bflo(v.x); a[1] += bfhi(v.x);
    a[2] += bflo(v.y); a[3] += bfhi(v.y);
    a[4] += bflo(v.z); a[5] += bfhi(v.z);
    a[6] += bflo(v.w); a[7] += bfhi(v.w);
}

// ---------- CSR build ----------
__global__ void k_hist(const int* __restrict__ dst, int E, int* __restrict__ cnt) {
    int i = blockIdx.x * 256 + threadIdx.x;
    if (i < E) atomicAdd(&cnt[dst[i]], 1);
}

__global__ void k_alloc(const int* __restrict__ cnt, int n, int* __restrict__ off,
                        int* __restrict__ total) {
    int i = blockIdx.x * 256 + threadIdx.x;
    int lane = threadIdx.x & 63;
    int v = (i < n) ? cnt[i] : 0;
    int s = v;
    #pragma unroll
    for (int d = 1; d < 64; d <<= 1) {
        int t = __shfl_up(s, d, 64);
        if (lane >= d) s += t;
    }
    int excl = s - v;
    int wtot = __shfl(s, 63, 64);
    int base = 0;
    if (lane == 63) base = atomicAdd(total, wtot);
    base = __shfl(base, 63, 64);
    if (i < n) off[i] = base + excl;
}

__global__ void k_scatter(const int* __restrict__ src, const int* __restrict__ dst, int E,
                          const int* __restrict__ off, int* __restrict__ cur,
                          int* __restrict__ sidx) {
    int i = blockIdx.x * 256 + threadIdx.x;
    if (i < E) {
        int d = dst[i];
        int p = atomicAdd(&cur[d], 1);
        sidx[off[d] + p] = src[i];
    }
}

// ---------- weight concat + bf16 convert: Wcat[384][256] = [Wl; Wr; Wres] ----------
__global__ void k_wconv(const float* __restrict__ Wl, const float* __restrict__ Wr,
                        const float* __restrict__ Wres, bf16* __restrict__ Wcat) {
    int i = blockIdx.x * 256 + threadIdx.x;   // element-group of 4
    int base = i * 4;
    if (base >= 384 * 256) return;
    int r = base >> 8;
    int c = base & 255;
    const float* W = (r < 128) ? Wl : ((r < 256) ? Wr : Wres);
    float4 v = *(const float4*)&W[(size_t)(r & 127) * 256 + c];
    bf16* o = &Wcat[base];
    o[0] = (bf16)v.x; o[1] = (bf16)v.y; o[2] = (bf16)v.z; o[3] = (bf16)v.w;
}

// ---------- MFMA GEMM: [y | z] = x @ Wcat^T (BM=64, BN=384, BK=32, A-dbuf, B from L1) ----------
__global__ __launch_bounds__(256) void k_gemm(const float* __restrict__ x,
                                              const bf16* __restrict__ Wcat, int n,
                                              bf16* __restrict__ y, bf16* __restrict__ z) {
    __shared__ __align__(16) bf16 smem[64 * 392];   // 49 KB: Cs; first 8 KB doubles as As[2]
    bf16* Cs = smem;

    int t = threadIdx.x;
    int wv = t >> 6, lane = t & 63;
    int node0 = blockIdx.x * 64;

    f32x4 acc[4][6] = {};

    // A staging: thread -> (row = t>>2, kg = t&3); 8 floats -> bf16x8 chunk
    int a_row = t >> 2;
    int a_kg = t & 3;
    int a_gr = node0 + a_row;
    const float* a_src = &x[(size_t)a_gr * DIN + a_kg * 8];
    // swizzled chunk byte offset within a 64x32 tile
    int a_wbyte = a_row * 64 + ((a_kg ^ ((a_row >> 1) & 3)) << 4);

    // B fragment base: row c = wv*96 + nn*16 + (lane&15), k = s*32 + (lane>>4)*8
    const bf16* wb = Wcat + ((size_t)(wv * 96 + (lane & 15))) * DIN + ((lane >> 4) << 3);

    // A fragment read offsets (swizzled), kg = lane>>4
    int fr_kg = lane >> 4;
    int fr_byte[4];
    #pragma unroll
    for (int m = 0; m < 4; m++) {
        int r = m * 16 + (lane & 15);
        fr_byte[m] = r * 64 + ((fr_kg ^ ((r >> 1) & 3)) << 4);
    }

    // prologue: stage step 0
    {
        float4 v0, v1;
        if (a_gr < n) {
            v0 = *(const float4*)a_src;
            v1 = *(const float4*)(a_src + 4);
        } else { v0 = make_float4(0, 0, 0, 0); v1 = v0; }
        *(bf16x8*)((char*)smem + a_wbyte) = cvt8(v0, v1);
    }
    __syncthreads();

    for (int s = 0; s < 8; ++s) {
        int cur = s & 1;
        // issue next-step global loads (overlap with compute below)
        float4 v0, v1;
        if (s < 7) {
            if (a_gr < n) {
                v0 = *(const float4*)(a_src + (s + 1) * 32);
                v1 = *(const float4*)(a_src + (s + 1) * 32 + 4);
            } else { v0 = make_float4(0, 0, 0, 0); v1 = v0; }
        }
        // B frags from global (L1-resident slice)
        bf16x8 bfr[6];
        #pragma unroll
        for (int nn = 0; nn < 6; nn++)
            bfr[nn] = *(const bf16x8*)(wb + (size_t)nn * 16 * DIN + s * 32);
        // A frags from LDS
        bf16x8 afr[4];
        #pragma unroll
        for (int m = 0; m < 4; m++)
            afr[m] = *(const bf16x8*)((char*)smem + cur * 4096 + fr_byte[m]);
        #pragma unroll
        for (int m = 0; m < 4; m++)
            #pragma unroll
            for (int nn = 0; nn < 6; nn++)
                acc[m][nn] = __builtin_amdgcn_mfma_f32_16x16x32_bf16(
                    afr[m], bfr[nn], acc[m][nn], 0, 0, 0);
        if (s < 7)
            *(bf16x8*)((char*)smem + (cur ^ 1) * 4096 + a_wbyte) = cvt8(v0, v1);
        __syncthreads();
    }

    // acc -> Cs (bf16); C/D layout: col=lane&15, row=(lane>>4)*4+j
    #pragma unroll
    for (int m = 0; m < 4; m++) {
        #pragma unroll
        for (int nn = 0; nn < 6; nn++) {
            int col = wv * 96 + nn * 16 + (lane & 15);
            int r0 = m * 16 + ((lane >> 4) << 2);
            #pragma unroll
            for (int j = 0; j < 4; j++)
                Cs[(r0 + j) * 392 + col] = (bf16)acc[m][nn][j];
        }
    }
    __syncthreads();

    // coalesced stores: per row, 4 threads cover contiguous 64B per iteration
    {
        int r = t >> 2;
        int gr = node0 + r;
        if (gr < n) {
            #pragma unroll
            for (int u = 0; u < 4; u++) {
                int c = (t & 3) * 8 + u * 32;
                uint4 v = *(const uint4*)&Cs[r * 392 + c];
                *(uint4*)&y[(size_t)gr * HDIM + c] = v;
            }
            #pragma unroll
            for (int u = 0; u < 8; u++) {
                int c = (t & 3) * 8 + u * 32;
                uint4 v = *(const uint4*)&Cs[r * 392 + 128 + c];
                *(uint4*)&z[(size_t)gr * 2 * HDIM + c] = v;
            }
        }
    }
}

// ---------- fused gather + epilogue: one wave per node, pipelined 16B/lane gather ----------
__global__ __launch_bounds__(256) void k_gather(
    const bf16* __restrict__ y, const bf16* __restrict__ z,
    const int* __restrict__ off, const int* __restrict__ cnt, const int* __restrict__ sidx,
    const float* __restrict__ bl, const float* __restrict__ bres,
    const float* __restrict__ wscore, const float* __restrict__ bscore,
    const float* __restrict__ wcrit, const float* __restrict__ bcrit,
    const float* __restrict__ rrs, const float* __restrict__ palpha,
    int n, float* __restrict__ outF, float* __restrict__ outL)
{
    __shared__ float ws[(NCRIT + 1) * HDIM];
    int t = threadIdx.x;
    for (int i = t; i < (NCRIT + 1) * HDIM; i += 256) {
        int q = i >> 7, c = i & 127;
        ws[i] = (q == 0) ? wscore[c] : wcrit[(size_t)(q - 1) * HDIM + c];
    }
    __syncthreads();

    int node = blockIdx.x * 4 + (t >> 6);
    if (node >= n) return;
    int lane = t & 63;
    int q4 = lane >> 4;    // edge slot within batch
    int c16 = lane & 15;   // column group: cols c16*8 .. c16*8+7

    // issue node-local streaming loads early (consumed after the gather loop)
    uint4 zr = *(const uint4*)&z[(size_t)node * 2 * HDIM + c16 * 8];
    uint4 zs = *(const uint4*)&z[(size_t)node * 2 * HDIM + HDIM + c16 * 8];
    float4 b0 = *(const float4*)&bl[c16 * 8];
    float4 b1 = *(const float4*)&bl[c16 * 8 + 4];
    float4 r0 = *(const float4*)&bres[c16 * 8];
    float4 r1 = *(const float4*)&bres[c16 * 8 + 4];

    const char* ybase = (const char*)y + c16 * 16;
    int beg = off[node], len = cnt[node];

    float a[8] = {};
    if (len > 0) {
        const int* sp = sidx + beg;
        int nb = (len + 7) >> 3;   // batches of 8 edges
        int lm1 = len - 1;
        int e0a = q4,     e0b = 4 + q4;
        int ia = sp[e0a < len ? e0a : lm1];
        int ib = sp[e0b < len ? e0b : lm1];
        uint4 va = *(const uint4*)(ybase + ((size_t)(unsigned)ia << 8));
        uint4 vb = *(const uint4*)(ybase + ((size_t)(unsigned)ib << 8));
        int ja = 0, jb = 0;
        if (nb > 1) {
            int e1a = 8 + q4, e1b = 12 + q4;
            ja = sp[e1a < len ? e1a : lm1];
            jb = sp[e1b < len ? e1b : lm1];
        }
        for (int b = 0; b < nb; ++b) {
            uint4 wa = va, wb2 = vb;
            int ka = 0, kb = 0;
            if (b + 1 < nb) {
                wa  = *(const uint4*)(ybase + ((size_t)(unsigned)ja << 8));
                wb2 = *(const uint4*)(ybase + ((size_t)(unsigned)jb << 8));
            }
            if (b + 2 < nb) {
                int e2a = (b + 2) * 8 + q4, e2b = (b + 2) * 8 + 4 + q4;
                ka = sp[e2a < len ? e2a : lm1];
                kb = sp[e2b < len ? e2b : lm1];
            }
            int e = b * 8 + q4;
            if (e < len) acc8(a, va);
            if (e + 4 < len) acc8(a, vb);
            va = wa; vb = wb2; ja = ka; jb = kb;
        }
    }

    // combine the 4 quarter-sums
    #pragma unroll
    for (int j = 0; j < 8; j++) {
        a[j] += __shfl_xor(a[j], 16, 64);
        a[j] += __shfl_xor(a[j], 32, 64);
    }
    float inv = 1.f / fmaxf((float)len, 1.f);

    float zl[8] = {bflo(zr.x), bfhi(zr.x), bflo(zr.y), bfhi(zr.y),
                   bflo(zr.z), bfhi(zr.z), bflo(zr.w), bfhi(zr.w)};
    float zv[8] = {bflo(zs.x), bfhi(zs.x), bflo(zs.y), bfhi(zs.y),
                   bflo(zs.z), bfhi(zs.z), bflo(zs.w), bfhi(zs.w)};
    float blv[8] = {b0.x, b0.y, b0.z, b0.w, b1.x, b1.y, b1.z, b1.w};
    float brv[8] = {r0.x, r0.y, r0.z, r0.w, r1.x, r1.y, r1.z, r1.w};

    float h[8];
    #pragma unroll
    for (int j = 0; j < 8; j++)
        h[j] = fmaxf(a[j] * inv + blv[j] + zl[j], 0.f) + zv[j] + brv[j];

    float p[NCRIT + 1];
    #pragma unroll
    for (int q = 0; q < NCRIT + 1; q++) {
        const float* wp = &ws[q * HDIM + c16 * 8];
        float s = 0.f;
        #pragma unroll
        for (int j = 0; j < 8; j++) s += h[j] * wp[j];
        p[q] = s;
    }
    #pragma unroll
    for (int q = 0; q < NCRIT + 1; q++) {
        #pragma unroll
        for (int d = 8; d >= 1; d >>= 1)
            p[q] += __shfl_xor(p[q], d, 64);
    }
    if (lane == 0) {
        float al = palpha[0];
        float aa = 1.f / (1.f + expf(-al));
        outF[node] = aa * rrs[node] + (1.f - aa) * (p[0] + bscore[0]);
        #pragma unroll
        for (int q = 1; q < NCRIT + 1; q++)
            outL[(size_t)node * NCRIT + q - 1] = p[q] + bcrit[q - 1];
    }
}

extern "C" void kernel_launch(void* const* d_in, const int* in_sizes, int n_in,
                              void* d_out, int out_size, void* d_ws, size_t ws_size,
                              hipStream_t stream) {
    const float* x      = (const float*)d_in[0];
    const int*   ei     = (const int*)d_in[1];
    const float* rrs    = (const float*)d_in[2];
    const float* Wl     = (const float*)d_in[3];
    const float* bl     = (const float*)d_in[4];
    const float* Wr     = (const float*)d_in[5];
    const float* Wres   = (const float*)d_in[6];
    const float* bres   = (const float*)d_in[7];
    const float* wscore = (const float*)d_in[8];
    const float* bscore = (const float*)d_in[9];
    const float* wcrit  = (const float*)d_in[10];
    const float* bcrit  = (const float*)d_in[11];
    const float* alpha  = (const float*)d_in[12];

    int N = in_sizes[0] / DIN;
    int E = in_sizes[1] / 2;
    const int* srcv = ei;
    const int* dstv = ei + E;

    char* p = (char*)d_ws;
    int* cnt   = (int*)p; p += alignup((size_t)N * 4, 256);
    int* cur   = (int*)p; p += alignup((size_t)N * 4, 256);
    int* total = (int*)p; p += 256;
    int* off   = (int*)p; p += alignup((size_t)N * 4, 256);
    int* sidx  = (int*)p; p += alignup((size_t)E * 4, 256);
    bf16* Wcat = (bf16*)p; p += alignup((size_t)384 * DIN * 2, 256);
    bf16* y    = (bf16*)p; p += alignup((size_t)N * HDIM * 2, 256);
    bf16* z    = (bf16*)p; p += alignup((size_t)N * 2 * HDIM * 2, 256);

    hipMemsetAsync(cnt, 0, (size_t)N * 4, stream);
    hipMemsetAsync(cur, 0, (size_t)N * 4, stream);
    hipMemsetAsync(total, 0, 256, stream);

    k_hist<<<(E + 255) / 256, 256, 0, stream>>>(dstv, E, cnt);
    k_alloc<<<(N + 255) / 256, 256, 0, stream>>>(cnt, N, off, total);
    k_scatter<<<(E + 255) / 256, 256, 0, stream>>>(srcv, dstv, E, off, cur, sidx);
    k_wconv<<<(384 * 256 / 4 + 255) / 256, 256, 0, stream>>>(Wl, Wr, Wres, Wcat);

    k_gemm<<<(N + 63) / 64, 256, 0, stream>>>(x, Wcat, N, y, z);

    float* outF = (float*)d_out;
    float* outL = outF + N;
    k_gather<<<(N + 3) / 4, 256, 0, stream>>>(y, z, off, cnt, sidx, bl, bres,
                                              wscore, bscore, wcrit, bcrit,
                                              rrs, alpha, N, outF, outL);
}

// Round 5
// 293.402 us; speedup vs baseline: 2.1654x; 1.3249x over previous
//
#include <hip/hip_runtime.h>
#include <math.h>

#define DIN 256
#define HDIM 128
#define NCRIT 10

typedef __bf16 bf16;
typedef bf16 bf16x8 __attribute__((ext_vector_type(8)));
typedef float f32x4 __attribute__((ext_vector_type(4)));

static inline size_t alignup(size_t x, size_t a) { return (x + a - 1) & ~(a - 1); }

__device__ inline float bflo(unsigned v) { return __uint_as_float(v << 16); }
__device__ inline float bfhi(unsigned v) { return __uint_as_float(v & 0xffff0000u); }

__device__ inline bf16x8 cvt8(float4 v0, float4 v1) {
    bf16x8 w;
    w[0] = (bf16)v0.x; w[1] = (bf16)v0.y; w[2] = (bf16)v0.z; w[3] = (bf16)v0.w;
    w[4] = (bf16)v1.x; w[5] = (bf16)v1.y; w[6] = (bf16)v1.z; w[7] = (bf16)v1.w;
    return w;
}

__device__ inline void gl_lds16(const void* g, void* l) {
    __builtin_amdgcn_global_load_lds(
        (const __attribute__((address_space(1))) unsigned*)g,
        (__attribute__((address_space(3))) unsigned*)l, 16, 0, 0);
}

// ---------- CSR build (single atomic pass) ----------
__global__ void k_hist(const int* __restrict__ dst, int E, int* __restrict__ cnt,
                       int* __restrict__ epos) {
    int i = blockIdx.x * 256 + threadIdx.x;
    if (i < E) epos[i] = atomicAdd(&cnt[dst[i]], 1);
}

__global__ void k_alloc(const int* __restrict__ cnt, int n, int* __restrict__ off,
                        int* __restrict__ total) {
    int i = blockIdx.x * 256 + threadIdx.x;
    int lane = threadIdx.x & 63;
    int v = (i < n) ? cnt[i] : 0;
    int s = v;
    #pragma unroll
    for (int d = 1; d < 64; d <<= 1) {
        int t = __shfl_up(s, d, 64);
        if (lane >= d) s += t;
    }
    int excl = s - v;
    int wtot = __shfl(s, 63, 64);
    int base = 0;
    if (lane == 63) base = atomicAdd(total, wtot);
    base = __shfl(base, 63, 64);
    if (i < n) off[i] = base + excl;
}

__global__ void k_scatter(const int* __restrict__ src, const int* __restrict__ dst,
                          const int* __restrict__ epos, int E,
                          const int* __restrict__ off, int* __restrict__ sidx) {
    int i = blockIdx.x * 256 + threadIdx.x;
    if (i < E) sidx[off[dst[i]] + epos[i]] = src[i];
}

// ---------- weight concat + bf16 convert: Wcat[384][256] = [Wl; Wr; Wres] ----------
__global__ void k_wconv(const float* __restrict__ Wl, const float* __restrict__ Wr,
                        const float* __restrict__ Wres, bf16* __restrict__ Wcat) {
    int i = blockIdx.x * 256 + threadIdx.x;
    int base = i * 4;
    if (base >= 384 * 256) return;
    int r = base >> 8;
    int c = base & 255;
    const float* W = (r < 128) ? Wl : ((r < 256) ? Wr : Wres);
    float4 v = *(const float4*)&W[(size_t)(r & 127) * 256 + c];
    bf16* o = &Wcat[base];
    o[0] = (bf16)v.x; o[1] = (bf16)v.y; o[2] = (bf16)v.z; o[3] = (bf16)v.w;
}

// ---------- MFMA GEMM: [y|z] = x @ Wcat^T, BM=64 BN=384 BK=32, dbuf + global_load_lds ----------
// LDS bytes: bufB0 [0,24576) bufB1 [24576,49152) bufA0 [49152,53248) bufA1 [53248,57344)
// B layout per buf: [kg 0..3][c 0..383][16B]  (byte = kg*6144 + c*16)
// A layout per buf: [kq 0..3][r ^ (kq<<1)][16B] (byte = kq*1024 + (r^(kq<<1))*16)
__global__ __launch_bounds__(256) void k_gemm(const float* __restrict__ x,
                                              const bf16* __restrict__ Wcat, int n,
                                              bf16* __restrict__ y, bf16* __restrict__ z) {
    __shared__ __align__(16) char smem[57344];
    int t = threadIdx.x;
    int wv = t >> 6, lane = t & 63;
    int node0 = blockIdx.x * 64;

    f32x4 acc[4][6] = {};

    // A staging mapping: thread -> (row, kq)
    int a_r = t >> 2, a_kq = t & 3;
    int a_gr = node0 + a_r;
    const float* a_src = &x[(size_t)a_gr * DIN + a_kq * 8];
    int a_woff = a_kq * 1024 + ((a_r ^ (a_kq << 1)) << 4);

    // B DMA mapping: 6 issues x 256 threads x 16B = 24KB
    int gOff[6];
    const char* wcb = (const char*)Wcat;
    #pragma unroll
    for (int i = 0; i < 6; i++) {
        int LL = i * 256 + t;
        int kg = LL / 384;
        int c = LL - kg * 384;
        gOff[i] = c * 512 + kg * 16;
    }

    // fragment read offsets
    int f_kg = lane >> 4, f_l15 = lane & 15;
    int aRd[4];
    #pragma unroll
    for (int m = 0; m < 4; m++) {
        int r = m * 16 + f_l15;
        aRd[m] = f_kg * 1024 + ((r ^ (f_kg << 1)) << 4);
    }
    int bRd[6];
    #pragma unroll
    for (int nn = 0; nn < 6; nn++) {
        int c = wv * 96 + nn * 16 + f_l15;
        bRd[nn] = f_kg * 6144 + c * 16;
    }

    // prologue: stage tile 0
    {
        float4 v0, v1;
        if (a_gr < n) { v0 = *(const float4*)a_src; v1 = *(const float4*)(a_src + 4); }
        else { v0 = make_float4(0, 0, 0, 0); v1 = v0; }
        *(bf16x8*)(smem + 49152 + a_woff) = cvt8(v0, v1);
        #pragma unroll
        for (int i = 0; i < 6; i++)
            gl_lds16(wcb + gOff[i], smem + i * 4096 + wv * 1024);
    }
    __syncthreads();

    #pragma unroll 2
    for (int s = 0; s < 8; ++s) {
        int cur = s & 1;
        float4 v0, v1;
        if (s < 7) {
            if (a_gr < n) {
                v0 = *(const float4*)(a_src + (s + 1) * 32);
                v1 = *(const float4*)(a_src + (s + 1) * 32 + 4);
            } else { v0 = make_float4(0, 0, 0, 0); v1 = v0; }
            #pragma unroll
            for (int i = 0; i < 6; i++)
                gl_lds16(wcb + gOff[i] + (s + 1) * 64,
                         smem + (cur ^ 1) * 24576 + i * 4096 + wv * 1024);
        }
        bf16x8 afr[4], bfr[6];
        #pragma unroll
        for (int m = 0; m < 4; m++)
            afr[m] = *(const bf16x8*)(smem + 49152 + cur * 4096 + aRd[m]);
        #pragma unroll
        for (int nn = 0; nn < 6; nn++)
            bfr[nn] = *(const bf16x8*)(smem + cur * 24576 + bRd[nn]);
        #pragma unroll
        for (int m = 0; m < 4; m++)
            #pragma unroll
            for (int nn = 0; nn < 6; nn++)
                acc[m][nn] = __builtin_amdgcn_mfma_f32_16x16x32_bf16(
                    afr[m], bfr[nn], acc[m][nn], 0, 0, 0);
        if (s < 7)
            *(bf16x8*)(smem + 49152 + (cur ^ 1) * 4096 + a_woff) = cvt8(v0, v1);
        __syncthreads();
    }

    // epilogue: acc -> Cs (bf16); C/D layout: col=lane&15, row=(lane>>4)*4+j
    bf16* Cs = (bf16*)smem;
    #pragma unroll
    for (int m = 0; m < 4; m++) {
        #pragma unroll
        for (int nn = 0; nn < 6; nn++) {
            int col = wv * 96 + nn * 16 + f_l15;
            int r0 = m * 16 + (f_kg << 2);
            #pragma unroll
            for (int j = 0; j < 4; j++)
                Cs[(r0 + j) * 392 + col] = (bf16)acc[m][nn][j];
        }
    }
    __syncthreads();

    {
        int r = t >> 2;
        int gr = node0 + r;
        if (gr < n) {
            #pragma unroll
            for (int u = 0; u < 4; u++) {
                int c = (t & 3) * 8 + u * 32;
                uint4 v = *(const uint4*)&Cs[r * 392 + c];
                *(uint4*)&y[(size_t)gr * HDIM + c] = v;
            }
            #pragma unroll
            for (int u = 0; u < 8; u++) {
                int c = (t & 3) * 8 + u * 32;
                uint4 v = *(const uint4*)&Cs[r * 392 + 128 + c];
                *(uint4*)&z[(size_t)gr * 2 * HDIM + c] = v;
            }
        }
    }
}

// ---------- fused gather + epilogue: one wave per node, 8B/lane (2 rows/instr) ----------
__global__ __launch_bounds__(256) void k_gather(
    const bf16* __restrict__ y, const bf16* __restrict__ z,
    const int* __restrict__ off, const int* __restrict__ cnt, const int* __restrict__ sidx,
    const float* __restrict__ bl, const float* __restrict__ bres,
    const float* __restrict__ wscore, const float* __restrict__ bscore,
    const float* __restrict__ wcrit, const float* __restrict__ bcrit,
    const float* __restrict__ rrs, const float* __restrict__ palpha,
    int n, float* __restrict__ outF, float* __restrict__ outL)
{
    __shared__ bf16 wsb[11 * 128];
    int t = threadIdx.x;
    for (int i = t; i < 11 * 128; i += 256) {
        int q = i >> 7, c = i & 127;
        wsb[i] = (bf16)((q == 0) ? wscore[c] : wcrit[(size_t)(q - 1) * HDIM + c]);
    }
    __syncthreads();

    int node = blockIdx.x * 4 + (t >> 6);
    if (node >= n) return;
    int lane = t & 63, r2 = lane >> 5, c32 = lane & 31;

    // node-local loads issued early
    uint2 zr = *(const uint2*)&z[(size_t)node * 2 * HDIM + c32 * 4];
    uint2 zs = *(const uint2*)&z[(size_t)node * 2 * HDIM + HDIM + c32 * 4];
    float4 blv = *(const float4*)&bl[c32 * 4];
    float4 brv = *(const float4*)&bres[c32 * 4];

    const char* ybase = (const char*)y + c32 * 8;
    int beg = off[node], len = cnt[node];
    const int* sp = sidx + beg;

    float a0 = 0.f, a1 = 0.f, a2 = 0.f, a3 = 0.f;
    int e = 0;
    for (; e + 8 <= len; e += 8) {
        int i0 = sp[e + r2];
        int i1 = sp[e + 2 + r2];
        int i2 = sp[e + 4 + r2];
        int i3 = sp[e + 6 + r2];
        uint2 v0 = *(const uint2*)(ybase + ((size_t)(unsigned)i0 << 8));
        uint2 v1 = *(const uint2*)(ybase + ((size_t)(unsigned)i1 << 8));
        uint2 v2 = *(const uint2*)(ybase + ((size_t)(unsigned)i2 << 8));
        uint2 v3 = *(const uint2*)(ybase + ((size_t)(unsigned)i3 << 8));
        a0 += bflo(v0.x) + bflo(v1.x) + bflo(v2.x) + bflo(v3.x);
        a1 += bfhi(v0.x) + bfhi(v1.x) + bfhi(v2.x) + bfhi(v3.x);
        a2 += bflo(v0.y) + bflo(v1.y) + bflo(v2.y) + bflo(v3.y);
        a3 += bfhi(v0.y) + bfhi(v1.y) + bfhi(v2.y) + bfhi(v3.y);
    }
    for (; e < len; e += 2) {
        int slot = e + r2;
        int ii = sp[slot < len ? slot : len - 1];
        uint2 v = *(const uint2*)(ybase + ((size_t)(unsigned)ii << 8));
        if (slot < len) {
            a0 += bflo(v.x); a1 += bfhi(v.x);
            a2 += bflo(v.y); a3 += bfhi(v.y);
        }
    }
    a0 += __shfl_xor(a0, 32, 64);
    a1 += __shfl_xor(a1, 32, 64);
    a2 += __shfl_xor(a2, 32, 64);
    a3 += __shfl_xor(a3, 32, 64);
    float inv = 1.f / fmaxf((float)len, 1.f);

    float h0 = fmaxf(a0 * inv + blv.x + bflo(zr.x), 0.f) + bflo(zs.x) + brv.x;
    float h1 = fmaxf(a1 * inv + blv.y + bfhi(zr.x), 0.f) + bfhi(zs.x) + brv.y;
    float h2 = fmaxf(a2 * inv + blv.z + bflo(zr.y), 0.f) + bflo(zs.y) + brv.z;
    float h3 = fmaxf(a3 * inv + blv.w + bfhi(zr.y), 0.f) + bfhi(zs.y) + brv.w;

    // split epilogue: half r2=0 handles q=0..5, half r2=1 handles q=6..10
    float p[6];
    #pragma unroll
    for (int qq = 0; qq < 6; qq++) {
        int q = r2 * 6 + qq;
        float s = 0.f;
        if (q < 11) {
            uint2 w = *(const uint2*)&wsb[q * 128 + c32 * 4];
            s = h0 * bflo(w.x) + h1 * bfhi(w.x) + h2 * bflo(w.y) + h3 * bfhi(w.y);
        }
        #pragma unroll
        for (int d = 1; d < 32; d <<= 1)
            s += __shfl_xor(s, d, 64);
        p[qq] = s;
    }
    if ((lane & 31) == 0) {
        if (r2 == 0) {
            float al = palpha[0];
            float aa = 1.f / (1.f + expf(-al));
            outF[node] = aa * rrs[node] + (1.f - aa) * (p[0] + bscore[0]);
            #pragma unroll
            for (int qq = 1; qq < 6; qq++)
                outL[(size_t)node * NCRIT + qq - 1] = p[qq] + bcrit[qq - 1];
        } else {
            #pragma unroll
            for (int qq = 0; qq < 5; qq++)
                outL[(size_t)node * NCRIT + 5 + qq] = p[qq] + bcrit[5 + qq];
        }
    }
}

extern "C" void kernel_launch(void* const* d_in, const int* in_sizes, int n_in,
                              void* d_out, int out_size, void* d_ws, size_t ws_size,
                              hipStream_t stream) {
    const float* x      = (const float*)d_in[0];
    const int*   ei     = (const int*)d_in[1];
    const float* rrs    = (const float*)d_in[2];
    const float* Wl     = (const float*)d_in[3];
    const float* bl     = (const float*)d_in[4];
    const float* Wr     = (const float*)d_in[5];
    const float* Wres   = (const float*)d_in[6];
    const float* bres   = (const float*)d_in[7];
    const float* wscore = (const float*)d_in[8];
    const float* bscore = (const float*)d_in[9];
    const float* wcrit  = (const float*)d_in[10];
    const float* bcrit  = (const float*)d_in[11];
    const float* alpha  = (const float*)d_in[12];

    int N = in_sizes[0] / DIN;
    int E = in_sizes[1] / 2;
    const int* srcv = ei;
    const int* dstv = ei + E;

    char* p = (char*)d_ws;
    int* cnt   = (int*)p; p += alignup((size_t)N * 4, 256);
    int* total = (int*)p; p += 256;
    int* off   = (int*)p; p += alignup((size_t)N * 4, 256);
    int* epos  = (int*)p; p += alignup((size_t)E * 4, 256);
    int* sidx  = (int*)p; p += alignup((size_t)E * 4, 256);
    bf16* Wcat = (bf16*)p; p += alignup((size_t)384 * DIN * 2, 256);
    bf16* y    = (bf16*)p; p += alignup((size_t)N * HDIM * 2, 256);
    bf16* z    = (bf16*)p; p += alignup((size_t)N * 2 * HDIM * 2, 256);

    hipMemsetAsync(cnt, 0, (size_t)N * 4, stream);
    hipMemsetAsync(total, 0, 256, stream);

    k_hist<<<(E + 255) / 256, 256, 0, stream>>>(dstv, E, cnt, epos);
    k_alloc<<<(N + 255) / 256, 256, 0, stream>>>(cnt, N, off, total);
    k_scatter<<<(E + 255) / 256, 256, 0, stream>>>(srcv, dstv, epos, E, off, sidx);
    k_wconv<<<(384 * 256 / 4 + 255) / 256, 256, 0, stream>>>(Wl, Wr, Wres, Wcat);

    k_gemm<<<(N + 63) / 64, 256, 0, stream>>>(x, Wcat, N, y, z);

    float* outF = (float*)d_out;
    float* outL = outF + N;
    k_gather<<<(N + 3) / 4, 256, 0, stream>>>(y, z, off, cnt, sidx, bl, bres,
                                              wscore, bscore, wcrit, bcrit,
                                              rrs, alpha, N, outF, outL);
}